// Round 6
// baseline (56.940 us; speedup 1.0000x reference)
//
#include <hip/hip_runtime.h>

#define NPIX 65536
#define NB 8
#define NN 64
#define KK 32
#define LOG2E 1.4426950408889634f

typedef _Float16 half2v __attribute__((ext_vector_type(2)));

__device__ __forceinline__ float rcpf(float x) { return __builtin_amdgcn_rcpf(x); }
__device__ __forceinline__ float exp2_fast(float x) { float r; asm("v_exp_f32 %0, %1" : "=v"(r) : "v"(x)); return r; }
__device__ __forceinline__ float log2_fast(float x) { float r; asm("v_log_f32 %0, %1" : "=v"(r) : "v"(x)); return r; }

#if __has_builtin(__builtin_amdgcn_fdot2)
__device__ __forceinline__ float fdot2(half2v a, half2v b, float c) {
    return __builtin_amdgcn_fdot2(a, b, c, false);
}
#else
__device__ __forceinline__ float fdot2(half2v a, half2v b, float c) {
    return fmaf((float)a[1], (float)b[1], fmaf((float)a[0], (float)b[0], c));
}
#endif

__device__ __forceinline__ void load_row_f16(const float4* p, half2v* A) {
#pragma unroll
    for (int j = 0; j < 8; ++j) {
        float4 v = p[j];
        half2v ha, hb;
        ha[0] = (_Float16)v.x; ha[1] = (_Float16)v.y;
        hb[0] = (_Float16)v.z; hb[1] = (_Float16)v.w;
        A[2 * j] = ha; A[2 * j + 1] = hb;
    }
}

// Phase 1: fc[b,pix] = 1 - S2/(S1+1e-5).
// Block = 256 threads = 4 image rows of one batch. Half-block h (128 thr)
// owns rows (4*rq + 2h, 4*rq + 2h + 1); thread t handles 4 pixels:
// (r0,t), (r0,t+128), (r0+1,t), (r0+1,t+128).
// Per n: 5 LDS-read issues serve 64 fdot2 (8 indep chains) + 12 trans;
// dx^2 shared between the row pair (2 subs + 2 muls serve 4 gaussians).
__global__ __launch_bounds__(256) void k_phase1(
    const float* __restrict__ loc,    // [B,N,4]
    const float* __restrict__ masks,  // [B,N,K]
    const float* __restrict__ proto,  // [B,H,W,K]
    const float* __restrict__ conf,   // [B,N]
    float* __restrict__ fcb)          // [B, NPIX]
{
    __shared__ float4 smaskf[NN * 4];  // masks * -log2e as f16 pairs (4 KB)
    __shared__ float4 sprm[2][NN];     // per half-block: cx, gx, ey_r0, ey_r1

    const int b   = blockIdx.x >> 6;   // 8 batches x 64 row-quads = 512 blocks
    const int rq  = blockIdx.x & 63;
    const int tid = threadIdx.x;
    const int h   = tid >> 7;          // half-block (wave-uniform)
    const int t   = tid & 127;

    const float inv = 1.0f / 256.0f;

    // --- stage masks (f16, scaled by -log2e): 256 threads x 1 float4 write ---
    {
        const float4* m4 = (const float4*)(masks + (size_t)b * NN * KK);
        float4 u0 = m4[tid * 2], u1 = m4[tid * 2 + 1];
        union { float4 f; half2v h2[4]; } w;
        w.h2[0][0] = (_Float16)(u0.x * -LOG2E); w.h2[0][1] = (_Float16)(u0.y * -LOG2E);
        w.h2[1][0] = (_Float16)(u0.z * -LOG2E); w.h2[1][1] = (_Float16)(u0.w * -LOG2E);
        w.h2[2][0] = (_Float16)(u1.x * -LOG2E); w.h2[2][1] = (_Float16)(u1.y * -LOG2E);
        w.h2[3][0] = (_Float16)(u1.z * -LOG2E); w.h2[3][1] = (_Float16)(u1.w * -LOG2E);
        smaskf[tid] = w.f;
    }
    // --- stage per-(h,n) folded params ---
    if (tid < 128) {
        const int n  = tid & 63;
        const int hh = tid >> 6;
        float4 L = ((const float4*)loc)[b * NN + n];
        float isx = rcpf(L.z), isy = rcpf(L.w);
        float gx = -0.72134752f * isx * isx;   // -0.5*log2(e)/sx^2
        float gy = -0.72134752f * isy * isy;
        float lc = log2_fast(conf[b * NN + n]);
        const int r0 = rq * 4 + hh * 2;
        float dy0 = (r0 + 0.5f) * inv - L.y;
        float dy1 = (r0 + 1.5f) * inv - L.y;
        sprm[hh][n] = make_float4(L.x, gx,
                                  fmaf(dy0 * dy0, gy, lc),
                                  fmaf(dy1 * dy1, gy, lc));
    }
    __syncthreads();

    const int r0  = rq * 4 + h * 2;
    const int px0 = r0 * 256 + t;      // (r0, t)
    // px1 = px0+128 (r0, t+128); px2 = px0+256 (r0+1, t); px3 = px0+384
    const float fx0 = (t + 0.5f) * inv;
    const float fx1 = (t + 128 + 0.5f) * inv;

    const float* pbase = proto + ((size_t)b * NPIX + px0) * KK;
    half2v A0[16], A1[16], A2[16], A3[16];
    load_row_f16((const float4*)(pbase),            A0);
    load_row_f16((const float4*)(pbase + 128 * KK), A1);
    load_row_f16((const float4*)(pbase + 256 * KK), A2);
    load_row_f16((const float4*)(pbase + 384 * KK), A3);

    float S10 = 0.f, S20 = 0.f, S11 = 0.f, S21 = 0.f;
    float S12 = 0.f, S22 = 0.f, S13 = 0.f, S23 = 0.f;

#pragma unroll 2
    for (int n = 0; n < NN; ++n) {
        const float4 P = sprm[h][n];
        union { float4 f[4]; half2v h2[16]; } mk;
        mk.f[0] = smaskf[n * 4 + 0];
        mk.f[1] = smaskf[n * 4 + 1];
        mk.f[2] = smaskf[n * 4 + 2];
        mk.f[3] = smaskf[n * 4 + 3];

        float sA0 = 0.f, sB0 = 0.f, sA1 = 0.f, sB1 = 0.f;
        float sA2 = 0.f, sB2 = 0.f, sA3 = 0.f, sB3 = 0.f;
#pragma unroll
        for (int j = 0; j < 16; j += 2) {
            half2v m0 = mk.h2[j], m1 = mk.h2[j + 1];
            sA0 = fdot2(A0[j], m0, sA0); sB0 = fdot2(A0[j + 1], m1, sB0);
            sA1 = fdot2(A1[j], m0, sA1); sB1 = fdot2(A1[j + 1], m1, sB1);
            sA2 = fdot2(A2[j], m0, sA2); sB2 = fdot2(A2[j + 1], m1, sB2);
            sA3 = fdot2(A3[j], m0, sA3); sB3 = fdot2(A3[j + 1], m1, sB3);
        }
        const float dx0 = fx0 - P.x, dx1 = fx1 - P.x;
        const float q0 = dx0 * dx0, q1 = dx1 * dx1;
        const float g0 = exp2_fast(fmaf(q0, P.y, P.z));   // (r0, t)
        const float g1 = exp2_fast(fmaf(q1, P.y, P.z));   // (r0, t+128)
        const float g2 = exp2_fast(fmaf(q0, P.y, P.w));   // (r0+1, t)
        const float g3 = exp2_fast(fmaf(q1, P.y, P.w));   // (r0+1, t+128)
        const float u0 = exp2_fast(sA0 + sB0);
        const float u1 = exp2_fast(sA1 + sB1);
        const float u2 = exp2_fast(sA2 + sB2);
        const float u3 = exp2_fast(sA3 + sB3);
        const float a0 = g0 * rcpf(1.0f + u0);
        const float a1 = g1 * rcpf(1.0f + u1);
        const float a2 = g2 * rcpf(1.0f + u2);
        const float a3 = g3 * rcpf(1.0f + u3);
        S10 += a0; S20 = fmaf(a0, a0, S20);
        S11 += a1; S21 = fmaf(a1, a1, S21);
        S12 += a2; S22 = fmaf(a2, a2, S22);
        S13 += a3; S23 = fmaf(a3, a3, S23);
    }
    float* o = fcb + (size_t)b * NPIX + px0;
    o[0]   = 1.0f - S20 * rcpf(S10 + 1e-5f);
    o[128] = 1.0f - S21 * rcpf(S11 + 1e-5f);
    o[256] = 1.0f - S22 * rcpf(S12 + 1e-5f);
    o[384] = 1.0f - S23 * rcpf(S13 + 1e-5f);
}

// Phase 2: weighted-variance sum -> scalar. One thread = one pixel, all 3
// channels (fcb read once; traffic fcb 2MB + original 6.3MB).
__global__ __launch_bounds__(256) void k_phase2(
    const float* __restrict__ original,  // [B,3,H,W]
    const float* __restrict__ fcb,       // [B, NPIX]
    float* __restrict__ out)
{
    const int pix = blockIdx.x * 256 + threadIdx.x;

    float f[NB];
    float tot = 0.f;
#pragma unroll
    for (int b = 0; b < NB; ++b) { f[b] = fcb[(size_t)b * NPIX + pix]; tot += f[b]; }

    float part = 0.f;
#pragma unroll
    for (int c = 0; c < 3; ++c) {
        float o[NB];
        float wm = 0.f;
#pragma unroll
        for (int b = 0; b < NB; ++b) {
            o[b] = original[((size_t)(b * 3 + c)) * NPIX + pix];
            wm = fmaf(o[b], f[b], wm);
        }
#pragma unroll
        for (int b = 0; b < NB; ++b) {
            float d = o[b] - wm;
            part = fmaf(d * d, f[b], part);
        }
    }
    part *= rcpf(tot);

#pragma unroll
    for (int off = 32; off > 0; off >>= 1) part += __shfl_down(part, off);
    __shared__ float sred[4];
    if ((threadIdx.x & 63) == 0) sred[threadIdx.x >> 6] = part;
    __syncthreads();
    if (threadIdx.x == 0) atomicAdd(out, sred[0] + sred[1] + sred[2] + sred[3]);
}

// Fallback: fully fused scalar path, only if ws_size too small (shouldn't happen).
__global__ __launch_bounds__(256) void k_fused(
    const float* __restrict__ original, const float* __restrict__ loc,
    const float* __restrict__ masks, const float* __restrict__ proto,
    const float* __restrict__ conf, float* __restrict__ out)
{
    const int pix = blockIdx.x * 256 + threadIdx.x;
    const float inv = 1.0f / 256.0f;
    const float fx = ((pix & 255) + 0.5f) * inv;
    const float fy = ((pix >> 8) + 0.5f) * inv;

    float f[NB];
    for (int b = 0; b < NB; ++b) {
        const float4* p4 = (const float4*)(proto + ((size_t)b * NPIX + pix) * KK);
        const float4* m4 = (const float4*)(masks + (size_t)b * NN * KK);
        const float4* l4 = (const float4*)(loc + (size_t)b * NN * 4);
        const float*  cf = conf + b * NN;
        float S1 = 0.f, S2 = 0.f;
        for (int n = 0; n < NN; ++n) {
            float sa = 0.f;
#pragma unroll
            for (int j = 0; j < 8; ++j) {
                float4 A = p4[j], m = m4[n * 8 + j];
                sa = fmaf(A.w, m.w, fmaf(A.z, m.z, fmaf(A.y, m.y, fmaf(A.x, m.x, sa))));
            }
            const float4 L = l4[n];
            float isx = rcpf(L.z), isy = rcpf(L.w);
            float dx = (fx - L.x) * isx, dy = (fy - L.y) * isy;
            float g = __expf(-0.5f * fmaf(dx, dx, dy * dy));
            float a = g * rcpf(1.0f + __expf(-sa)) * cf[n];
            S1 += a;
            S2 = fmaf(a, a, S2);
        }
        f[b] = 1.0f - S2 * rcpf(S1 + 1e-5f);
    }
    float tot = 0.f;
#pragma unroll
    for (int b = 0; b < NB; ++b) tot += f[b];
    float part = 0.f;
#pragma unroll
    for (int c = 0; c < 3; ++c) {
        float o[NB];
        float wm = 0.f;
#pragma unroll
        for (int b = 0; b < NB; ++b) {
            o[b] = original[((size_t)(b * 3 + c)) * NPIX + pix];
            wm = fmaf(o[b], f[b], wm);
        }
#pragma unroll
        for (int b = 0; b < NB; ++b) {
            float d = o[b] - wm;
            part = fmaf(d * d, f[b], part);
        }
    }
    part *= rcpf(tot);

#pragma unroll
    for (int off = 32; off > 0; off >>= 1) part += __shfl_down(part, off);
    __shared__ float sred[4];
    if ((threadIdx.x & 63) == 0) sred[threadIdx.x >> 6] = part;
    __syncthreads();
    if (threadIdx.x == 0) atomicAdd(out, sred[0] + sred[1] + sred[2] + sred[3]);
}

extern "C" void kernel_launch(void* const* d_in, const int* in_sizes, int n_in,
                              void* d_out, int out_size, void* d_ws, size_t ws_size,
                              hipStream_t stream) {
    const float* original = (const float*)d_in[0];
    const float* loc      = (const float*)d_in[1];
    const float* masks    = (const float*)d_in[2];
    const float* proto    = (const float*)d_in[3];
    const float* conf     = (const float*)d_in[4];
    float* out = (float*)d_out;

    hipMemsetAsync(out, 0, sizeof(float), stream);

    const size_t fc_bytes = (size_t)NB * NPIX * sizeof(float);
    if (ws_size >= fc_bytes) {
        float* fcb = (float*)d_ws;
        k_phase1<<<NB * 64, 256, 0, stream>>>(loc, masks, proto, conf, fcb);
        k_phase2<<<NPIX / 256, 256, 0, stream>>>(original, fcb, out);
    } else {
        k_fused<<<NPIX / 256, 256, 0, stream>>>(original, loc, masks, proto, conf, out);
    }
}

// Round 7
// 51.735 us; speedup vs baseline: 1.1006x; 1.1006x over previous
//
#include <hip/hip_runtime.h>
#include <hip/hip_bf16.h>

#define NPIX 65536
#define NB 8
#define NN 64
#define KK 32
#define LOG2E 1.4426950408889634f
#define SCW 68   // LDS score row stride (dwords): 16B-aligned, breaks pow2 banks

typedef __attribute__((ext_vector_type(4))) float f32x4;
typedef __attribute__((ext_vector_type(8))) short bf16x8;

__device__ __forceinline__ float rcpf(float x) { return __builtin_amdgcn_rcpf(x); }
__device__ __forceinline__ float exp2_fast(float x) { float r; asm("v_exp_f32 %0, %1" : "=v"(r) : "v"(x)); return r; }
__device__ __forceinline__ float log2_fast(float x) { float r; asm("v_log_f32 %0, %1" : "=v"(r) : "v"(x)); return r; }
__device__ __forceinline__ short f2bf(float x) {
    union { __hip_bfloat16 b; short s; } u; u.b = __float2bfloat16(x); return u.s;
}

// Phase 1 via MFMA, layout-probed.
// Block = 256 thr = 4 waves = one image row of one batch. Wave w owns 64 px.
// scores = proto_px[16x32] . masksT[32x16] per tile via mfma_f32_16x16x32_bf16.
// A one-time probe MFMA (D[m][n] = m + 16n exact) measures the HW
// (lane,reg)->(m,n) mapping; scores are scattered to LDS at probed addresses,
// then evaluated with clean indexing. No layout assumptions survive.
__global__ __launch_bounds__(256) void k_phase1(
    const float* __restrict__ loc,    // [B,N,4]
    const float* __restrict__ masks,  // [B,N,K]
    const float* __restrict__ proto,  // [B,H,W,K]
    const float* __restrict__ conf,   // [B,N]
    float* __restrict__ fcb)          // [B, NPIX]
{
    __shared__ float4 sprm[NN];          // cx, gx, ey(row), pad
    __shared__ float  sc[4][16 * SCW];   // per-wave score scratch (17 KB)

    const int b    = blockIdx.x >> 8;    // wave-uniform
    const int row  = blockIdx.x & 255;
    const int tid  = threadIdx.x;
    const int lane = tid & 63;
    const int wave = tid >> 6;
    const int nl   = lane & 15;
    const int kg   = lane >> 4;

    const float inv = 1.0f / 256.0f;
    const float fy  = (row + 0.5f) * inv;

    // ---- per-(b,n) folded params for this row ----
    if (tid < NN) {
        float4 L = ((const float4*)loc)[b * NN + tid];
        float isx = rcpf(L.z), isy = rcpf(L.w);
        float gx = -0.72134752f * isx * isx;   // -0.5*log2e/sx^2
        float gy = -0.72134752f * isy * isy;
        float dy = fy - L.y;
        float ey = fmaf(dy * dy, gy, log2_fast(conf[b * NN + tid]));
        sprm[tid] = make_float4(L.x, gx, ey, 0.f);
    }
    __syncthreads();

    // ---- probe: measure (lane,reg) -> (m,n) of the MFMA C/D layout ----
    int mi[4], ni[4];
    {
        bf16x8 Ap, Bp;
#pragma unroll
        for (int j = 0; j < 8; ++j) { Ap[j] = 0; Bp[j] = 0; }
        if (kg == 0) {
            Ap[0] = f2bf((float)nl);        // A[m][0] = m
            Ap[1] = f2bf(1.0f);             // A[m][1] = 1
            Bp[0] = f2bf(1.0f);             // B[0][n] = 1
            Bp[1] = f2bf((float)(16 * nl)); // B[1][n] = 16n (exact in bf16)
        }
        f32x4 z = {0.f, 0.f, 0.f, 0.f};
        f32x4 d = __builtin_amdgcn_mfma_f32_16x16x32_bf16(Ap, Bp, z, 0, 0, 0);
#pragma unroll
        for (int r = 0; r < 4; ++r) {
            int v = (int)(d[r] + 0.5f);     // D[m][n] = m + 16n, 0..255
            mi[r] = v & 15;
            ni[r] = (v >> 4) & 15;
        }
    }

    // ---- B fragments: masks * -log2e, bf16, 4 n-tiles (held all kernel) ----
    bf16x8 Bf[4];
#pragma unroll
    for (int t = 0; t < 4; ++t) {
        const float* mp = masks + ((size_t)b * NN + 16 * t + nl) * KK + kg * 8;
        float4 u0 = *(const float4*)mp;
        float4 u1 = *(const float4*)(mp + 4);
        bf16x8 v;
        v[0] = f2bf(u0.x * -LOG2E); v[1] = f2bf(u0.y * -LOG2E);
        v[2] = f2bf(u0.z * -LOG2E); v[3] = f2bf(u0.w * -LOG2E);
        v[4] = f2bf(u1.x * -LOG2E); v[5] = f2bf(u1.y * -LOG2E);
        v[6] = f2bf(u1.z * -LOG2E); v[7] = f2bf(u1.w * -LOG2E);
        Bf[t] = v;
    }

    float* mysc = &sc[wave][0];
    const int pl = lane >> 2;           // eval: pixel-in-tile (4 lanes/px)
    const int ng = lane & 3;            // eval: n-block (16 n's each)

    for (int i = 0; i < 4; ++i) {
        const int cb = wave * 64 + i * 16;   // column base of this 16-px tile
        // A fragment: proto rows for pixels cb+nl, k = kg*8..+8
        const float* pp = proto + ((size_t)b * NPIX + row * 256 + cb + nl) * KK + kg * 8;
        float4 a0 = *(const float4*)pp;
        float4 a1 = *(const float4*)(pp + 4);
        bf16x8 Af;
        Af[0] = f2bf(a0.x); Af[1] = f2bf(a0.y); Af[2] = f2bf(a0.z); Af[3] = f2bf(a0.w);
        Af[4] = f2bf(a1.x); Af[5] = f2bf(a1.y); Af[6] = f2bf(a1.z); Af[7] = f2bf(a1.w);

        f32x4 z = {0.f, 0.f, 0.f, 0.f};
        f32x4 acc0 = __builtin_amdgcn_mfma_f32_16x16x32_bf16(Af, Bf[0], z, 0, 0, 0);
        f32x4 acc1 = __builtin_amdgcn_mfma_f32_16x16x32_bf16(Af, Bf[1], z, 0, 0, 0);
        f32x4 acc2 = __builtin_amdgcn_mfma_f32_16x16x32_bf16(Af, Bf[2], z, 0, 0, 0);
        f32x4 acc3 = __builtin_amdgcn_mfma_f32_16x16x32_bf16(Af, Bf[3], z, 0, 0, 0);

        // scatter scores to LDS at probed (m, n) addresses
#pragma unroll
        for (int r = 0; r < 4; ++r) {
            const int base = mi[r] * SCW + ni[r];
            mysc[base]      = acc0[r];
            mysc[base + 16] = acc1[r];
            mysc[base + 32] = acc2[r];
            mysc[base + 48] = acc3[r];
        }

        // eval: lane -> pixel (cb+pl), n in [ng*16, ng*16+16)
        const float fx = (cb + pl + 0.5f) * inv;
        float S1 = 0.f, S2 = 0.f;
        const float* scp = mysc + pl * SCW + ng * 16;
#pragma unroll
        for (int jj = 0; jj < 4; ++jj) {
            float4 s4 = *(const float4*)(scp + jj * 4);
            const int n0 = ng * 16 + jj * 4;
            {
                float4 P = sprm[n0 + 0];
                float dx = fx - P.x;
                float g  = exp2_fast(fmaf(dx * dx, P.y, P.z));
                float a  = g * rcpf(1.0f + exp2_fast(s4.x));
                S1 += a; S2 = fmaf(a, a, S2);
            }
            {
                float4 P = sprm[n0 + 1];
                float dx = fx - P.x;
                float g  = exp2_fast(fmaf(dx * dx, P.y, P.z));
                float a  = g * rcpf(1.0f + exp2_fast(s4.y));
                S1 += a; S2 = fmaf(a, a, S2);
            }
            {
                float4 P = sprm[n0 + 2];
                float dx = fx - P.x;
                float g  = exp2_fast(fmaf(dx * dx, P.y, P.z));
                float a  = g * rcpf(1.0f + exp2_fast(s4.z));
                S1 += a; S2 = fmaf(a, a, S2);
            }
            {
                float4 P = sprm[n0 + 3];
                float dx = fx - P.x;
                float g  = exp2_fast(fmaf(dx * dx, P.y, P.z));
                float a  = g * rcpf(1.0f + exp2_fast(s4.w));
                S1 += a; S2 = fmaf(a, a, S2);
            }
        }
        // reduce the 4 n-blocks of each pixel (lanes 4*pl .. 4*pl+3)
        S1 += __shfl_xor(S1, 1); S1 += __shfl_xor(S1, 2);
        S2 += __shfl_xor(S2, 1); S2 += __shfl_xor(S2, 2);
        if (ng == 0)
            fcb[(size_t)b * NPIX + row * 256 + cb + pl] = 1.0f - S2 * rcpf(S1 + 1e-5f);
    }
}

// Phase 2: weighted-variance sum -> scalar. One thread = one pixel, all 3
// channels (fcb read once; traffic fcb 2MB + original 6.3MB).
__global__ __launch_bounds__(256) void k_phase2(
    const float* __restrict__ original,  // [B,3,H,W]
    const float* __restrict__ fcb,       // [B, NPIX]
    float* __restrict__ out)
{
    const int pix = blockIdx.x * 256 + threadIdx.x;

    float f[NB];
    float tot = 0.f;
#pragma unroll
    for (int b = 0; b < NB; ++b) { f[b] = fcb[(size_t)b * NPIX + pix]; tot += f[b]; }

    float part = 0.f;
#pragma unroll
    for (int c = 0; c < 3; ++c) {
        float o[NB];
        float wm = 0.f;
#pragma unroll
        for (int b = 0; b < NB; ++b) {
            o[b] = original[((size_t)(b * 3 + c)) * NPIX + pix];
            wm = fmaf(o[b], f[b], wm);
        }
#pragma unroll
        for (int b = 0; b < NB; ++b) {
            float d = o[b] - wm;
            part = fmaf(d * d, f[b], part);
        }
    }
    part *= rcpf(tot);

#pragma unroll
    for (int off = 32; off > 0; off >>= 1) part += __shfl_down(part, off);
    __shared__ float sred[4];
    if ((threadIdx.x & 63) == 0) sred[threadIdx.x >> 6] = part;
    __syncthreads();
    if (threadIdx.x == 0) atomicAdd(out, sred[0] + sred[1] + sred[2] + sred[3]);
}

// Fallback: fully fused scalar path, only if ws_size too small (shouldn't happen).
__global__ __launch_bounds__(256) void k_fused(
    const float* __restrict__ original, const float* __restrict__ loc,
    const float* __restrict__ masks, const float* __restrict__ proto,
    const float* __restrict__ conf, float* __restrict__ out)
{
    const int pix = blockIdx.x * 256 + threadIdx.x;
    const float inv = 1.0f / 256.0f;
    const float fx = ((pix & 255) + 0.5f) * inv;
    const float fy = ((pix >> 8) + 0.5f) * inv;

    float f[NB];
    for (int b = 0; b < NB; ++b) {
        const float4* p4 = (const float4*)(proto + ((size_t)b * NPIX + pix) * KK);
        const float4* m4 = (const float4*)(masks + (size_t)b * NN * KK);
        const float4* l4 = (const float4*)(loc + (size_t)b * NN * 4);
        const float*  cf = conf + b * NN;
        float S1 = 0.f, S2 = 0.f;
        for (int n = 0; n < NN; ++n) {
            float sa = 0.f;
#pragma unroll
            for (int j = 0; j < 8; ++j) {
                float4 A = p4[j], m = m4[n * 8 + j];
                sa = fmaf(A.w, m.w, fmaf(A.z, m.z, fmaf(A.y, m.y, fmaf(A.x, m.x, sa))));
            }
            const float4 L = l4[n];
            float isx = rcpf(L.z), isy = rcpf(L.w);
            float dx = (fx - L.x) * isx, dy = (fy - L.y) * isy;
            float g = __expf(-0.5f * fmaf(dx, dx, dy * dy));
            float a = g * rcpf(1.0f + __expf(-sa)) * cf[n];
            S1 += a;
            S2 = fmaf(a, a, S2);
        }
        f[b] = 1.0f - S2 * rcpf(S1 + 1e-5f);
    }
    float tot = 0.f;
#pragma unroll
    for (int b = 0; b < NB; ++b) tot += f[b];
    float part = 0.f;
#pragma unroll
    for (int c = 0; c < 3; ++c) {
        float o[NB];
        float wm = 0.f;
#pragma unroll
        for (int b = 0; b < NB; ++b) {
            o[b] = original[((size_t)(b * 3 + c)) * NPIX + pix];
            wm = fmaf(o[b], f[b], wm);
        }
#pragma unroll
        for (int b = 0; b < NB; ++b) {
            float d = o[b] - wm;
            part = fmaf(d * d, f[b], part);
        }
    }
    part *= rcpf(tot);

#pragma unroll
    for (int off = 32; off > 0; off >>= 1) part += __shfl_down(part, off);
    __shared__ float sred[4];
    if ((threadIdx.x & 63) == 0) sred[threadIdx.x >> 6] = part;
    __syncthreads();
    if (threadIdx.x == 0) atomicAdd(out, sred[0] + sred[1] + sred[2] + sred[3]);
}

extern "C" void kernel_launch(void* const* d_in, const int* in_sizes, int n_in,
                              void* d_out, int out_size, void* d_ws, size_t ws_size,
                              hipStream_t stream) {
    const float* original = (const float*)d_in[0];
    const float* loc      = (const float*)d_in[1];
    const float* masks    = (const float*)d_in[2];
    const float* proto    = (const float*)d_in[3];
    const float* conf     = (const float*)d_in[4];
    float* out = (float*)d_out;

    hipMemsetAsync(out, 0, sizeof(float), stream);

    const size_t fc_bytes = (size_t)NB * NPIX * sizeof(float);
    if (ws_size >= fc_bytes) {
        float* fcb = (float*)d_ws;
        k_phase1<<<NB * 256, 256, 0, stream>>>(loc, masks, proto, conf, fcb);
        k_phase2<<<NPIX / 256, 256, 0, stream>>>(original, fcb, out);
    } else {
        k_fused<<<NPIX / 256, 256, 0, stream>>>(original, loc, masks, proto, conf, out);
    }
}

// Round 8
// 38.236 us; speedup vs baseline: 1.4892x; 1.3530x over previous
//
#include <hip/hip_runtime.h>
#include <hip/hip_bf16.h>

#define NPIX 65536
#define NB 8
#define NN 64
#define KK 32
#define LOG2E 1.4426950408889634f

typedef __attribute__((ext_vector_type(4))) float f32x4;
typedef __attribute__((ext_vector_type(8))) short bf16x8;

__device__ __forceinline__ float rcpf(float x) { return __builtin_amdgcn_rcpf(x); }
__device__ __forceinline__ float exp2_fast(float x) { float r; asm("v_exp_f32 %0, %1" : "=v"(r) : "v"(x)); return r; }
__device__ __forceinline__ float log2_fast(float x) { float r; asm("v_log_f32 %0, %1" : "=v"(r) : "v"(x)); return r; }
__device__ __forceinline__ short f2bf(float x) {
    union { __hip_bfloat16 b; short s; } u; u.b = __float2bfloat16(x); return u.s;
}

// Phase 1 via MFMA, layout-probed, swapped operands.
// D = masks_tile[16n x 32k] . proto_tile[32k x 16px]: D rows = n, cols = pixel.
// Probe MFMA (D[m][n] = m + 16n exact) measures (lane,reg)->(row,col); each
// lane then owns ONE pixel (col ni0) and 16 n-scores (rows mi[r] x 4 tiles):
// the sigmoid*gauss eval is fully lane-local, no LDS round-trip, and the
// final S1/S2 only needs 2 shfl_xor (lanes l, l^16, l^32, l^48 share a pixel).
__global__ __launch_bounds__(256) void k_phase1(
    const float* __restrict__ loc,    // [B,N,4]
    const float* __restrict__ masks,  // [B,N,K]
    const float* __restrict__ proto,  // [B,H,W,K]
    const float* __restrict__ conf,   // [B,N]
    float* __restrict__ fcb)          // [B, NPIX]
{
    __shared__ float4 sprm[NN];          // cx, gx, ey(row), pad  (1 KB)

    const int b    = blockIdx.x >> 8;    // wave-uniform
    const int row  = blockIdx.x & 255;
    const int tid  = threadIdx.x;
    const int lane = tid & 63;
    const int wave = tid >> 6;
    const int nl   = lane & 15;
    const int kg   = lane >> 4;

    const float inv = 1.0f / 256.0f;
    const float fy  = (row + 0.5f) * inv;

    // ---- per-(b,n) folded params for this row ----
    if (tid < NN) {
        float4 L = ((const float4*)loc)[b * NN + tid];
        float isx = rcpf(L.z), isy = rcpf(L.w);
        float gx = -0.72134752f * isx * isx;   // -0.5*log2e/sx^2
        float gy = -0.72134752f * isy * isy;
        float dy = fy - L.y;
        float ey = fmaf(dy * dy, gy, log2_fast(conf[b * NN + tid]));
        sprm[tid] = make_float4(L.x, gx, ey, 0.f);
    }
    __syncthreads();

    // ---- probe: measure (lane,reg) -> (row m, col n) of the MFMA D layout ----
    int mi[4], ni[4];
    {
        bf16x8 Ap, Bp;
#pragma unroll
        for (int j = 0; j < 8; ++j) { Ap[j] = 0; Bp[j] = 0; }
        if (kg == 0) {
            Ap[0] = f2bf((float)nl);        // A[m][0] = m
            Ap[1] = f2bf(1.0f);             // A[m][1] = 1
            Bp[0] = f2bf(1.0f);             // B[0][n] = 1
            Bp[1] = f2bf((float)(16 * nl)); // B[1][n] = 16n (exact in bf16)
        }
        f32x4 z = {0.f, 0.f, 0.f, 0.f};
        f32x4 d = __builtin_amdgcn_mfma_f32_16x16x32_bf16(Ap, Bp, z, 0, 0, 0);
#pragma unroll
        for (int r = 0; r < 4; ++r) {
            int v = (int)(d[r] + 0.5f);     // D[m][n] = m + 16n, 0..255
            mi[r] = v & 15;
            ni[r] = (v >> 4) & 15;
        }
    }
    const int ni0 = ni[0];   // col (pixel slot) — constant across regs on CDNA

    // ---- mask fragments (first operand): rows n = 16t+nl, k = kg*8+j ----
    bf16x8 Mf[4];
#pragma unroll
    for (int t = 0; t < 4; ++t) {
        const float* mp = masks + ((size_t)b * NN + 16 * t + nl) * KK + kg * 8;
        float4 u0 = *(const float4*)mp;
        float4 u1 = *(const float4*)(mp + 4);
        bf16x8 v;
        v[0] = f2bf(u0.x * -LOG2E); v[1] = f2bf(u0.y * -LOG2E);
        v[2] = f2bf(u0.z * -LOG2E); v[3] = f2bf(u0.w * -LOG2E);
        v[4] = f2bf(u1.x * -LOG2E); v[5] = f2bf(u1.y * -LOG2E);
        v[6] = f2bf(u1.z * -LOG2E); v[7] = f2bf(u1.w * -LOG2E);
        Mf[t] = v;
    }

    // ---- hoist per-(t,r) prior params into registers (probed rows) ----
    float Pcx[4][4], Pgx[4][4], Pey[4][4];
#pragma unroll
    for (int t = 0; t < 4; ++t)
#pragma unroll
        for (int r = 0; r < 4; ++r) {
            float4 P = sprm[16 * t + mi[r]];   // broadcast read (uniform in 16-group)
            Pcx[t][r] = P.x; Pgx[t][r] = P.y; Pey[t][r] = P.z;
        }

#define EVALT(ACC, T)                                                      \
    {                                                                      \
        _Pragma("unroll") for (int r = 0; r < 4; ++r) {                    \
            float dx = fx - Pcx[T][r];                                     \
            float e  = fmaf(dx * dx, Pgx[T][r], Pey[T][r]);                \
            float a  = exp2_fast(e) * rcpf(1.0f + exp2_fast(ACC[r]));      \
            S1 += a; S2 = fmaf(a, a, S2);                                  \
        }                                                                  \
    }

    const size_t prow = (size_t)b * NPIX + row * 256;
    for (int i = 0; i < 4; ++i) {
        const int cb = wave * 64 + i * 16;    // 16-pixel tile base
        // proto fragment (second operand): cols px = cb+nl, k = kg*8+j
        const float* pp = proto + (prow + cb + nl) * KK + kg * 8;
        float4 a0 = *(const float4*)pp;
        float4 a1 = *(const float4*)(pp + 4);
        bf16x8 Pf;
        Pf[0] = f2bf(a0.x); Pf[1] = f2bf(a0.y); Pf[2] = f2bf(a0.z); Pf[3] = f2bf(a0.w);
        Pf[4] = f2bf(a1.x); Pf[5] = f2bf(a1.y); Pf[6] = f2bf(a1.z); Pf[7] = f2bf(a1.w);

        f32x4 z = {0.f, 0.f, 0.f, 0.f};
        f32x4 acc0 = __builtin_amdgcn_mfma_f32_16x16x32_bf16(Mf[0], Pf, z, 0, 0, 0);
        f32x4 acc1 = __builtin_amdgcn_mfma_f32_16x16x32_bf16(Mf[1], Pf, z, 0, 0, 0);
        f32x4 acc2 = __builtin_amdgcn_mfma_f32_16x16x32_bf16(Mf[2], Pf, z, 0, 0, 0);
        f32x4 acc3 = __builtin_amdgcn_mfma_f32_16x16x32_bf16(Mf[3], Pf, z, 0, 0, 0);

        const float fx = (cb + ni0 + 0.5f) * inv;  // this lane's pixel
        float S1 = 0.f, S2 = 0.f;
        EVALT(acc0, 0);
        EVALT(acc1, 1);
        EVALT(acc2, 2);
        EVALT(acc3, 3);

        // combine the 4 lanes (l, l^16, l^32, l^48) holding this pixel
        S1 += __shfl_xor(S1, 16); S1 += __shfl_xor(S1, 32);
        S2 += __shfl_xor(S2, 16); S2 += __shfl_xor(S2, 32);
        if (lane < 16)
            fcb[prow + cb + ni0] = 1.0f - S2 * rcpf(S1 + 1e-5f);
    }
#undef EVALT
}

// Phase 2: weighted-variance sum -> scalar. One thread = one pixel, all 3
// channels (fcb read once; traffic fcb 2MB + original 6.3MB).
__global__ __launch_bounds__(256) void k_phase2(
    const float* __restrict__ original,  // [B,3,H,W]
    const float* __restrict__ fcb,       // [B, NPIX]
    float* __restrict__ out)
{
    const int pix = blockIdx.x * 256 + threadIdx.x;

    float f[NB];
    float tot = 0.f;
#pragma unroll
    for (int b = 0; b < NB; ++b) { f[b] = fcb[(size_t)b * NPIX + pix]; tot += f[b]; }

    float part = 0.f;
#pragma unroll
    for (int c = 0; c < 3; ++c) {
        float o[NB];
        float wm = 0.f;
#pragma unroll
        for (int b = 0; b < NB; ++b) {
            o[b] = original[((size_t)(b * 3 + c)) * NPIX + pix];
            wm = fmaf(o[b], f[b], wm);
        }
#pragma unroll
        for (int b = 0; b < NB; ++b) {
            float d = o[b] - wm;
            part = fmaf(d * d, f[b], part);
        }
    }
    part *= rcpf(tot);

#pragma unroll
    for (int off = 32; off > 0; off >>= 1) part += __shfl_down(part, off);
    __shared__ float sred[4];
    if ((threadIdx.x & 63) == 0) sred[threadIdx.x >> 6] = part;
    __syncthreads();
    if (threadIdx.x == 0) atomicAdd(out, sred[0] + sred[1] + sred[2] + sred[3]);
}

// Fallback: fully fused scalar path, only if ws_size too small (shouldn't happen).
__global__ __launch_bounds__(256) void k_fused(
    const float* __restrict__ original, const float* __restrict__ loc,
    const float* __restrict__ masks, const float* __restrict__ proto,
    const float* __restrict__ conf, float* __restrict__ out)
{
    const int pix = blockIdx.x * 256 + threadIdx.x;
    const float inv = 1.0f / 256.0f;
    const float fx = ((pix & 255) + 0.5f) * inv;
    const float fy = ((pix >> 8) + 0.5f) * inv;

    float f[NB];
    for (int b = 0; b < NB; ++b) {
        const float4* p4 = (const float4*)(proto + ((size_t)b * NPIX + pix) * KK);
        const float4* m4 = (const float4*)(masks + (size_t)b * NN * KK);
        const float4* l4 = (const float4*)(loc + (size_t)b * NN * 4);
        const float*  cf = conf + b * NN;
        float S1 = 0.f, S2 = 0.f;
        for (int n = 0; n < NN; ++n) {
            float sa = 0.f;
#pragma unroll
            for (int j = 0; j < 8; ++j) {
                float4 A = p4[j], m = m4[n * 8 + j];
                sa = fmaf(A.w, m.w, fmaf(A.z, m.z, fmaf(A.y, m.y, fmaf(A.x, m.x, sa))));
            }
            const float4 L = l4[n];
            float isx = rcpf(L.z), isy = rcpf(L.w);
            float dx = (fx - L.x) * isx, dy = (fy - L.y) * isy;
            float g = __expf(-0.5f * fmaf(dx, dx, dy * dy));
            float a = g * rcpf(1.0f + __expf(-sa)) * cf[n];
            S1 += a;
            S2 = fmaf(a, a, S2);
        }
        f[b] = 1.0f - S2 * rcpf(S1 + 1e-5f);
    }
    float tot = 0.f;
#pragma unroll
    for (int b = 0; b < NB; ++b) tot += f[b];
    float part = 0.f;
#pragma unroll
    for (int c = 0; c < 3; ++c) {
        float o[NB];
        float wm = 0.f;
#pragma unroll
        for (int b = 0; b < NB; ++b) {
            o[b] = original[((size_t)(b * 3 + c)) * NPIX + pix];
            wm = fmaf(o[b], f[b], wm);
        }
#pragma unroll
        for (int b = 0; b < NB; ++b) {
            float d = o[b] - wm;
            part = fmaf(d * d, f[b], part);
        }
    }
    part *= rcpf(tot);

#pragma unroll
    for (int off = 32; off > 0; off >>= 1) part += __shfl_down(part, off);
    __shared__ float sred[4];
    if ((threadIdx.x & 63) == 0) sred[threadIdx.x >> 6] = part;
    __syncthreads();
    if (threadIdx.x == 0) atomicAdd(out, sred[0] + sred[1] + sred[2] + sred[3]);
}

extern "C" void kernel_launch(void* const* d_in, const int* in_sizes, int n_in,
                              void* d_out, int out_size, void* d_ws, size_t ws_size,
                              hipStream_t stream) {
    const float* original = (const float*)d_in[0];
    const float* loc      = (const float*)d_in[1];
    const float* masks    = (const float*)d_in[2];
    const float* proto    = (const float*)d_in[3];
    const float* conf     = (const float*)d_in[4];
    float* out = (float*)d_out;

    hipMemsetAsync(out, 0, sizeof(float), stream);

    const size_t fc_bytes = (size_t)NB * NPIX * sizeof(float);
    if (ws_size >= fc_bytes) {
        float* fcb = (float*)d_ws;
        k_phase1<<<NB * 256, 256, 0, stream>>>(loc, masks, proto, conf, fcb);
        k_phase2<<<NPIX / 256, 256, 0, stream>>>(original, fcb, out);
    } else {
        k_fused<<<NPIX / 256, 256, 0, stream>>>(original, loc, masks, proto, conf, out);
    }
}

// Round 9
// 35.558 us; speedup vs baseline: 1.6013x; 1.0753x over previous
//
#include <hip/hip_runtime.h>
#include <hip/hip_bf16.h>

#define NPIX 65536
#define NB 8
#define NN 64
#define KK 32
#define LOG2E 1.4426950408889634f

typedef __attribute__((ext_vector_type(4))) float f32x4;
typedef __attribute__((ext_vector_type(8))) short bf16x8;

__device__ __forceinline__ float rcpf(float x) { return __builtin_amdgcn_rcpf(x); }
__device__ __forceinline__ float exp2_fast(float x) { float r; asm("v_exp_f32 %0, %1" : "=v"(r) : "v"(x)); return r; }
__device__ __forceinline__ float log2_fast(float x) { float r; asm("v_log_f32 %0, %1" : "=v"(r) : "v"(x)); return r; }
__device__ __forceinline__ short f2bf(float x) {
    union { __hip_bfloat16 b; short s; } u; u.b = __float2bfloat16(x); return u.s;
}

// Phase 1 via MFMA, layout-probed, swapped operands (D rows = n, cols = pixel).
// Block = 256 thr = 4 waves = TWO image rows of one batch; wave w owns the
// (w&1) half (128 px = 8 tiles) of row rp*2 + (w>>1). Per-lane: one pixel
// column (probed ni0) and 16 n-scores per tile -> eval fully lane-local.
// Gaussian in quadratic form: e = (alpha*fx + beta)*fx + gamma (per-n consts).
// Proto loads staged one tile ahead to hide global latency.
__global__ __launch_bounds__(256) void k_phase1(
    const float* __restrict__ loc,    // [B,N,4]
    const float* __restrict__ masks,  // [B,N,K]
    const float* __restrict__ proto,  // [B,H,W,K]
    const float* __restrict__ conf,   // [B,N]
    float* __restrict__ fcb)          // [B, NPIX]
{
    __shared__ float4 sprm[2][NN];       // per row: alpha, beta, gamma, pad

    const int b    = blockIdx.x >> 7;    // 8 batches x 128 row-pairs
    const int rp   = blockIdx.x & 127;
    const int tid  = threadIdx.x;
    const int lane = tid & 63;
    const int wave = tid >> 6;
    const int nl   = lane & 15;
    const int kg   = lane >> 4;
    const int rw   = wave >> 1;          // row of the pair (wave-uniform)
    const int half = wave & 1;           // 128-px half    (wave-uniform)
    const int row  = rp * 2 + rw;

    const float inv = 1.0f / 256.0f;

    // ---- per-(row,n) folded quadratic params ----
    if (tid < 128) {
        const int rr = tid >> 6, n = tid & 63;
        float4 L = ((const float4*)loc)[b * NN + n];
        float isx = rcpf(L.z), isy = rcpf(L.w);
        float gx = -0.72134752f * isx * isx;   // -0.5*log2e/sx^2
        float gy = -0.72134752f * isy * isy;
        float fyr = (rp * 2 + rr + 0.5f) * inv;
        float dy  = fyr - L.y;
        float ey  = fmaf(dy * dy, gy, log2_fast(conf[b * NN + n]));
        float beta  = -2.0f * gx * L.x;
        float gamma = fmaf(gx * L.x, L.x, ey);
        sprm[rr][n] = make_float4(gx, beta, gamma, 0.f);
    }
    __syncthreads();

    // ---- probe: measure (lane,reg) -> (row m, col n) of the MFMA D layout ----
    int mi[4], ni[4];
    {
        bf16x8 Ap, Bp;
#pragma unroll
        for (int j = 0; j < 8; ++j) { Ap[j] = 0; Bp[j] = 0; }
        if (kg == 0) {
            Ap[0] = f2bf((float)nl);        // A[m][0] = m
            Ap[1] = f2bf(1.0f);             // A[m][1] = 1
            Bp[0] = f2bf(1.0f);             // B[0][n] = 1
            Bp[1] = f2bf((float)(16 * nl)); // B[1][n] = 16n (exact in bf16)
        }
        f32x4 z = {0.f, 0.f, 0.f, 0.f};
        f32x4 d = __builtin_amdgcn_mfma_f32_16x16x32_bf16(Ap, Bp, z, 0, 0, 0);
#pragma unroll
        for (int r = 0; r < 4; ++r) {
            int v = (int)(d[r] + 0.5f);     // D[m][n] = m + 16n, 0..255
            mi[r] = v & 15;
            ni[r] = (v >> 4) & 15;
        }
    }
    const int ni0 = ni[0];   // this lane's pixel slot within a 16-px tile

    // ---- mask fragments (first operand): rows n = 16t+nl, k = kg*8+j ----
    bf16x8 Mf[4];
#pragma unroll
    for (int t = 0; t < 4; ++t) {
        const float* mp = masks + ((size_t)b * NN + 16 * t + nl) * KK + kg * 8;
        float4 u0 = *(const float4*)mp;
        float4 u1 = *(const float4*)(mp + 4);
        bf16x8 v;
        v[0] = f2bf(u0.x * -LOG2E); v[1] = f2bf(u0.y * -LOG2E);
        v[2] = f2bf(u0.z * -LOG2E); v[3] = f2bf(u0.w * -LOG2E);
        v[4] = f2bf(u1.x * -LOG2E); v[5] = f2bf(u1.y * -LOG2E);
        v[6] = f2bf(u1.z * -LOG2E); v[7] = f2bf(u1.w * -LOG2E);
        Mf[t] = v;
    }

    // ---- hoist per-(t,r) quadratic params for this wave's row ----
    float Pa[4][4], Pb[4][4], Pc[4][4];
#pragma unroll
    for (int t = 0; t < 4; ++t)
#pragma unroll
        for (int r = 0; r < 4; ++r) {
            float4 P = sprm[rw][16 * t + mi[r]];
            Pa[t][r] = P.x; Pb[t][r] = P.y; Pc[t][r] = P.z;
        }

#define EVALT(ACC, T)                                                       \
    {                                                                       \
        _Pragma("unroll") for (int r = 0; r < 4; ++r) {                     \
            float e  = fmaf(fmaf(Pa[T][r], fx, Pb[T][r]), fx, Pc[T][r]);    \
            float aa = exp2_fast(e) * rcpf(1.0f + exp2_fast(ACC[r]));       \
            S1 += aa; S2 = fmaf(aa, aa, S2);                                \
        }                                                                   \
    }

    const size_t prow = (size_t)b * NPIX + (size_t)row * 256;
    const int pxb = half * 128;
    const float* pp0 = proto + (prow + pxb + nl) * KK + kg * 8;

    // staged 1-tile-ahead pipeline over 8 tiles
    float4 c0 = *(const float4*)(pp0);
    float4 c1 = *(const float4*)(pp0 + 4);

#pragma unroll
    for (int i = 0; i < 8; ++i) {
        float4 n0, n1;
        if (i < 7) {
            const float* np = pp0 + (size_t)(i + 1) * 16 * KK;
            n0 = *(const float4*)np;
            n1 = *(const float4*)(np + 4);
        }

        bf16x8 Pf;
        Pf[0] = f2bf(c0.x); Pf[1] = f2bf(c0.y); Pf[2] = f2bf(c0.z); Pf[3] = f2bf(c0.w);
        Pf[4] = f2bf(c1.x); Pf[5] = f2bf(c1.y); Pf[6] = f2bf(c1.z); Pf[7] = f2bf(c1.w);

        f32x4 z = {0.f, 0.f, 0.f, 0.f};
        f32x4 acc0 = __builtin_amdgcn_mfma_f32_16x16x32_bf16(Mf[0], Pf, z, 0, 0, 0);
        f32x4 acc1 = __builtin_amdgcn_mfma_f32_16x16x32_bf16(Mf[1], Pf, z, 0, 0, 0);
        f32x4 acc2 = __builtin_amdgcn_mfma_f32_16x16x32_bf16(Mf[2], Pf, z, 0, 0, 0);
        f32x4 acc3 = __builtin_amdgcn_mfma_f32_16x16x32_bf16(Mf[3], Pf, z, 0, 0, 0);

        const float fx = (pxb + i * 16 + ni0 + 0.5f) * inv;  // this lane's pixel
        float S1 = 0.f, S2 = 0.f;
        EVALT(acc0, 0);
        EVALT(acc1, 1);
        EVALT(acc2, 2);
        EVALT(acc3, 3);

        // combine the 4 lanes (l, l^16, l^32, l^48) holding this pixel
        S1 += __shfl_xor(S1, 16); S1 += __shfl_xor(S1, 32);
        S2 += __shfl_xor(S2, 16); S2 += __shfl_xor(S2, 32);
        if (lane < 16)
            fcb[prow + pxb + i * 16 + ni0] = 1.0f - S2 * rcpf(S1 + 1e-5f);

        if (i < 7) { c0 = n0; c1 = n1; }
    }
#undef EVALT
}

// Phase 2: weighted-variance sum -> scalar. One thread = one pixel, all 3
// channels (fcb read once; traffic fcb 2MB + original 6.3MB).
__global__ __launch_bounds__(256) void k_phase2(
    const float* __restrict__ original,  // [B,3,H,W]
    const float* __restrict__ fcb,       // [B, NPIX]
    float* __restrict__ out)
{
    const int pix = blockIdx.x * 256 + threadIdx.x;

    float f[NB];
    float tot = 0.f;
#pragma unroll
    for (int b = 0; b < NB; ++b) { f[b] = fcb[(size_t)b * NPIX + pix]; tot += f[b]; }

    float part = 0.f;
#pragma unroll
    for (int c = 0; c < 3; ++c) {
        float o[NB];
        float wm = 0.f;
#pragma unroll
        for (int b = 0; b < NB; ++b) {
            o[b] = original[((size_t)(b * 3 + c)) * NPIX + pix];
            wm = fmaf(o[b], f[b], wm);
        }
#pragma unroll
        for (int b = 0; b < NB; ++b) {
            float d = o[b] - wm;
            part = fmaf(d * d, f[b], part);
        }
    }
    part *= rcpf(tot);

#pragma unroll
    for (int off = 32; off > 0; off >>= 1) part += __shfl_down(part, off);
    __shared__ float sred[4];
    if ((threadIdx.x & 63) == 0) sred[threadIdx.x >> 6] = part;
    __syncthreads();
    if (threadIdx.x == 0) atomicAdd(out, sred[0] + sred[1] + sred[2] + sred[3]);
}

// Fallback: fully fused scalar path, only if ws_size too small (shouldn't happen).
__global__ __launch_bounds__(256) void k_fused(
    const float* __restrict__ original, const float* __restrict__ loc,
    const float* __restrict__ masks, const float* __restrict__ proto,
    const float* __restrict__ conf, float* __restrict__ out)
{
    const int pix = blockIdx.x * 256 + threadIdx.x;
    const float inv = 1.0f / 256.0f;
    const float fx = ((pix & 255) + 0.5f) * inv;
    const float fy = ((pix >> 8) + 0.5f) * inv;

    float f[NB];
    for (int b = 0; b < NB; ++b) {
        const float4* p4 = (const float4*)(proto + ((size_t)b * NPIX + pix) * KK);
        const float4* m4 = (const float4*)(masks + (size_t)b * NN * KK);
        const float4* l4 = (const float4*)(loc + (size_t)b * NN * 4);
        const float*  cf = conf + b * NN;
        float S1 = 0.f, S2 = 0.f;
        for (int n = 0; n < NN; ++n) {
            float sa = 0.f;
#pragma unroll
            for (int j = 0; j < 8; ++j) {
                float4 A = p4[j], m = m4[n * 8 + j];
                sa = fmaf(A.w, m.w, fmaf(A.z, m.z, fmaf(A.y, m.y, fmaf(A.x, m.x, sa))));
            }
            const float4 L = l4[n];
            float isx = rcpf(L.z), isy = rcpf(L.w);
            float dx = (fx - L.x) * isx, dy = (fy - L.y) * isy;
            float g = __expf(-0.5f * fmaf(dx, dx, dy * dy));
            float a = g * rcpf(1.0f + __expf(-sa)) * cf[n];
            S1 += a;
            S2 = fmaf(a, a, S2);
        }
        f[b] = 1.0f - S2 * rcpf(S1 + 1e-5f);
    }
    float tot = 0.f;
#pragma unroll
    for (int b = 0; b < NB; ++b) tot += f[b];
    float part = 0.f;
#pragma unroll
    for (int c = 0; c < 3; ++c) {
        float o[NB];
        float wm = 0.f;
#pragma unroll
        for (int b = 0; b < NB; ++b) {
            o[b] = original[((size_t)(b * 3 + c)) * NPIX + pix];
            wm = fmaf(o[b], f[b], wm);
        }
#pragma unroll
        for (int b = 0; b < NB; ++b) {
            float d = o[b] - wm;
            part = fmaf(d * d, f[b], part);
        }
    }
    part *= rcpf(tot);

#pragma unroll
    for (int off = 32; off > 0; off >>= 1) part += __shfl_down(part, off);
    __shared__ float sred[4];
    if ((threadIdx.x & 63) == 0) sred[threadIdx.x >> 6] = part;
    __syncthreads();
    if (threadIdx.x == 0) atomicAdd(out, sred[0] + sred[1] + sred[2] + sred[3]);
}

extern "C" void kernel_launch(void* const* d_in, const int* in_sizes, int n_in,
                              void* d_out, int out_size, void* d_ws, size_t ws_size,
                              hipStream_t stream) {
    const float* original = (const float*)d_in[0];
    const float* loc      = (const float*)d_in[1];
    const float* masks    = (const float*)d_in[2];
    const float* proto    = (const float*)d_in[3];
    const float* conf     = (const float*)d_in[4];
    float* out = (float*)d_out;

    hipMemsetAsync(out, 0, sizeof(float), stream);

    const size_t fc_bytes = (size_t)NB * NPIX * sizeof(float);
    if (ws_size >= fc_bytes) {
        float* fcb = (float*)d_ws;
        k_phase1<<<NB * 128, 256, 0, stream>>>(loc, masks, proto, conf, fcb);
        k_phase2<<<NPIX / 256, 256, 0, stream>>>(original, fcb, out);
    } else {
        k_fused<<<NPIX / 256, 256, 0, stream>>>(original, loc, masks, proto, conf, out);
    }
}